// Round 9
// baseline (216.001 us; speedup 1.0000x reference)
//
#include <hip/hip_runtime.h>
#include <hip/hip_bf16.h>
#include <cstdint>

typedef __bf16 bf16x8 __attribute__((ext_vector_type(8)));
typedef float f32x4 __attribute__((ext_vector_type(4)));
typedef float f32x16 __attribute__((ext_vector_type(16)));

#define MFMA16(a, b, c) __builtin_amdgcn_mfma_f32_16x16x32_bf16(a, b, c, 0, 0, 0)
#define MFMA32(a, b, c) __builtin_amdgcn_mfma_f32_32x32x16_bf16(a, b, c, 0, 0, 0)

__device__ __forceinline__ void gload_lds16(const void* g, void* l) {
  __builtin_amdgcn_global_load_lds(
      (const __attribute__((address_space(1))) unsigned int*)g,
      (__attribute__((address_space(3))) unsigned int*)l, 16, 0, 0);
}

__device__ __forceinline__ unsigned short f2bf(float x) {
  union { float f; uint32_t u; } v; v.f = x;
  uint32_t r = v.u + 0x7fff + ((v.u >> 16) & 1);
  return (unsigned short)(r >> 16);
}
__device__ __forceinline__ float bf2f(unsigned short h) {
  union { float f; uint32_t u; } v; v.u = ((uint32_t)h) << 16;
  return v.f;
}
__device__ __forceinline__ f32x16 fzero16() {
  f32x16 v;
#pragma unroll
  for (int i = 0; i < 16; ++i) v[i] = 0.f;
  return v;
}

// S-tile (f32x16, pre-scaled by sc*log2e via Q) -> exp2 -> two PV B-frags.
// ZERO cross-lane ops (V stored with matching key permutation in k_qkv).
__device__ __forceinline__ void ptrans(const f32x16& sv, float& rsum,
                                       bf16x8& f0, bf16x8& f1) {
  float ps[16];
#pragma unroll
  for (int r = 0; r < 16; ++r) ps[r] = __builtin_exp2f(sv[r]);
  float rs = 0.f;
#pragma unroll
  for (int r = 0; r < 16; ++r) rs += ps[r];
  rsum += rs;
  bf16x8 a, b;
#pragma unroll
  for (int r = 0; r < 8; ++r) a[r] = (__bf16)ps[r];
#pragma unroll
  for (int r = 0; r < 8; ++r) b[r] = (__bf16)ps[8 + r];
  f0 = a; f1 = b;
}

// ---------------- K1a: hidden_states -> bf16 ----------------
__global__ __launch_bounds__(256) void k_split(const float* __restrict__ x,
                                               unsigned short* __restrict__ hi, int n4) {
  int i = blockIdx.x * blockDim.x + threadIdx.x;
  if (i >= n4) return;
  float4 v = ((const float4*)x)[i];
  ushort4 h;
  h.x = f2bf(v.x); h.y = f2bf(v.y); h.z = f2bf(v.z); h.w = f2bf(v.w);
  ((ushort4*)hi)[i] = h;
}

// ------------ K1b: transpose weights -> bf16 (fused, z selects W) ------------
__global__ __launch_bounds__(256) void k_wsplit(
    const float* __restrict__ Wq, const float* __restrict__ Wk,
    const float* __restrict__ Wv, const float* __restrict__ Wo,
    unsigned short* __restrict__ WtqH, unsigned short* __restrict__ WtkH,
    unsigned short* __restrict__ WtvH, unsigned short* __restrict__ WtoH) {
  const int z = blockIdx.z;
  const float* W = (z == 0) ? Wq : (z == 1) ? Wk : (z == 2) ? Wv : Wo;
  unsigned short* WtH = (z == 0) ? WtqH : (z == 1) ? WtkH : (z == 2) ? WtvH : WtoH;
  __shared__ float tile[32][33];
  const int bx = blockIdx.x, by = blockIdx.y;
  const int tx = threadIdx.x & 31, ty = threadIdx.x >> 5;
#pragma unroll
  for (int i = 0; i < 4; ++i)
    tile[ty + i * 8][tx] = W[(size_t)(by * 32 + ty + i * 8) * 1024 + bx * 32 + tx];
  __syncthreads();
#pragma unroll
  for (int i = 0; i < 4; ++i) {
    float v = tile[tx][ty + i * 8];
    WtH[(size_t)(bx * 32 + ty + i * 8) * 1024 + by * 32 + tx] = f2bf(v);
  }
}

// ---------------- K2: QKV GEMM, plain bf16, global_load_lds staging ----------------
// K and V stored FRAG-LINEAR (see round 7): per 64-key kb-block the 8KB region
// is contiguous -> k_attn stages each kb-block with 4 coalesced global_load_lds.
__global__ __launch_bounds__(256, 2) void k_qkv(
    const unsigned short* __restrict__ hsH,
    const unsigned short* __restrict__ WqH, const unsigned short* __restrict__ WkH,
    const unsigned short* __restrict__ WvH, const float* __restrict__ freqs,
    unsigned short* __restrict__ qB, unsigned short* __restrict__ kB,
    unsigned short* __restrict__ vB) {
  __shared__ unsigned short Ah[128 * 32], Bh[128 * 32];  // 8KB each, 64B rows
  const int tid = threadIdx.x;
  const int bm = blockIdx.y, bn = blockIdx.x;
  const int w = bn >> 3;           // 0=q 1=k 2=v
  const int n0 = (bn & 7) * 128;
  const unsigned short* WH = (w == 0) ? WqH : (w == 1) ? WkH : WvH;
  const int lane = tid & 63, wave = tid >> 6;
  const int wm = (wave & 1) * 64, wn = (wave >> 1) * 64;
  const int l15 = lane & 15, lq = lane >> 4;

  f32x4 acc[4][4];
#pragma unroll
  for (int i = 0; i < 4; i++)
#pragma unroll
    for (int j = 0; j < 4; j++) acc[i][j] = (f32x4){0.f, 0.f, 0.f, 0.f};

  const char* baseA = (const char*)hsH + (size_t)(bm * 128) * 2048;
  const char* baseB = (const char*)WH + (size_t)n0 * 2048;
  const int off0 = tid << 4, row0 = off0 >> 6, seg0 = off0 & 63;
  const int off1 = (tid + 256) << 4, row1 = off1 >> 6, seg1 = off1 & 63;

  for (int k0 = 0; k0 < 1024; k0 += 32) {
    __syncthreads();
    gload_lds16(baseA + (size_t)row0 * 2048 + k0 * 2 + seg0, (char*)Ah + wave * 1024);
    gload_lds16(baseB + (size_t)row0 * 2048 + k0 * 2 + seg0, (char*)Bh + wave * 1024);
    gload_lds16(baseA + (size_t)row1 * 2048 + k0 * 2 + seg1,
                (char*)Ah + 4096 + wave * 1024);
    gload_lds16(baseB + (size_t)row1 * 2048 + k0 * 2 + seg1,
                (char*)Bh + 4096 + wave * 1024);
    __syncthreads();
    bf16x8 ah[4], bh[4];
#pragma unroll
    for (int i = 0; i < 4; ++i) {
      ah[i] = *(const bf16x8*)&Ah[(wm + i * 16 + l15) * 32 + lq * 8];
      bh[i] = *(const bf16x8*)&Bh[(wn + i * 16 + l15) * 32 + lq * 8];
    }
#pragma unroll
    for (int i = 0; i < 4; ++i)
#pragma unroll
      for (int j = 0; j < 4; ++j) acc[i][j] = MFMA16(ah[i], bh[j], acc[i][j]);
  }

  // epilogue: C/D layout col=lane&15, row=(lane>>4)*4+r. RoPE for q,k.
  // Softmax scale * log2(e) folded into Q (f32, commutes with RoPE rotation).
  unsigned short* dst = (w == 0) ? qB : (w == 1) ? kB : vB;
#pragma unroll
  for (int i = 0; i < 4; ++i) {
#pragma unroll
    for (int j = 0; j < 4; ++j) {
      int colw = n0 + wn + j * 16 + l15;
      int h = colw >> 6, d = colw & 63;
#pragma unroll
      for (int r = 0; r < 4; ++r) {
        int rowg = bm * 128 + wm + i * 16 + lq * 4 + r;
        int s = rowg & 2047, b = rowg >> 11;
        float val = acc[i][j][r];
        size_t bhb = (size_t)(b * 16 + h) * 131072;
        if (w < 2) {
          float partner = __shfl_xor(val, 1);
          int jj = d >> 1;
          float2 cssn = ((const float2*)freqs)[s * 32 + jj];
          float cs = cssn.x, sn = cssn.y;
          float res = (d & 1) ? (partner * sn + val * cs) : (val * cs - partner * sn);
          if (w == 0) {
            res *= 0.18033688011112042f;  // 0.125 * log2(e)
            dst[(((size_t)(b * 16 + h)) * 2048 + s) * 64 + d] = f2bf(res);
          } else {
            size_t off = (size_t)(s >> 10) * 65536 + ((s >> 6) & 15) * 4096 +
                         ((s >> 5) & 1) * 2048 + (d >> 4) * 512 +
                         ((s & 31) + 32 * ((d >> 3) & 1)) * 8 + (d & 7);
            dst[bhb + off] = f2bf(res);
          }
        } else {
          // key permutation within 16-groups (swap middle 4-blocks)
          int sp = (s & ~12) | ((s & 4) << 1) | ((s & 8) >> 1);
          size_t off = (size_t)(sp >> 10) * 65536 + ((sp >> 6) & 15) * 4096 +
                       (d >> 5) * 2048 + ((sp >> 4) & 3) * 512 +
                       ((d & 31) + 32 * ((sp >> 3) & 1)) * 8 + (sp & 7);
          dst[bhb + off] = f2bf(val);
        }
      }
    }
  }
}

// ------- K3: chunked attention, LDS-staged K/V + q-split: 4 blocks/CU -------
// Round-8 counters: VGPR=112 (<128) with LDS staging -> registers no longer
// bound occupancy; grid (512=2/CU) did. q-split: 16 q-tiles of 128 queries,
// 32 queries/wave, grid 1024 -> 4 blocks/CU = 16 waves/CU. K/V traffic is
// block-level LDS staging (4 gload_lds/kb), so q-split does NOT duplicate
// per-wave VMEM loads (round-1's failure mode) and writes no partials
// (round-5's failure mode). LDS 32KB x 4 blocks = 128KB <= 160KB.
// bid = xcd + 8*x + 128*hi; gg = xcd + 8*hi -> 16 blocks of a (bh,chunk)
// share bid%8 -> same XCD L2 for K/V.
__global__ __launch_bounds__(256, 4) void k_attn(
    const unsigned short* __restrict__ qB, const unsigned short* __restrict__ kB,
    const unsigned short* __restrict__ vB,
    unsigned short* __restrict__ c0, unsigned short* __restrict__ c1) {
  __shared__ unsigned short KV[2][8192];  // [buf][K 4096 | V 4096] = 16KB/buf
  const int tid = threadIdx.x, lane = tid & 63, wave = tid >> 6;
  const int l31 = lane & 31, lh = lane >> 5;
  const int bid = blockIdx.x;
  const int x = (bid >> 3) & 15;
  const int gg = (bid & 7) + 8 * (bid >> 7);
  const int bh = gg & 31;
  const int chunk = gg >> 5;
  const int q0 = x * 128 + wave * 32;
  const size_t base = (size_t)bh * 131072;

  // Q B-frags (pre-scaled in k_qkv): lane n=l31 -> query q0+l31, k=ks*16+lh*8
  bf16x8 qf[4];
#pragma unroll
  for (int ks = 0; ks < 4; ++ks)
    qf[ks] = *(const bf16x8*)(qB + base + (size_t)(q0 + l31) * 64 + ks * 16 + lh * 8);

  const unsigned short* kblk = kB + base + chunk * 65536;  // + kb*4096 elems (8KB)
  const unsigned short* vblk = vB + base + chunk * 65536;

  // prologue: stage kb=0 into buf 0
  gload_lds16((const char*)kblk + tid * 16, (char*)KV[0] + wave * 1024);
  gload_lds16((const char*)kblk + 4096 + tid * 16, (char*)KV[0] + 4096 + wave * 1024);
  gload_lds16((const char*)vblk + tid * 16, (char*)KV[0] + 8192 + wave * 1024);
  gload_lds16((const char*)vblk + 4096 + tid * 16, (char*)KV[0] + 12288 + wave * 1024);
  __syncthreads();

  f32x16 o[2];  // [dt]
#pragma unroll
  for (int a = 0; a < 2; ++a) o[a] = fzero16();
  float rsum = 0.f;

  for (int kb = 0; kb < 16; ++kb) {
    const unsigned short* Kc = KV[kb & 1];
    const unsigned short* Vc = KV[kb & 1] + 4096;
    // stage kb+1 into the other buffer (loads in flight across the compute)
    if (kb < 15) {
      const char* ks_ = (const char*)(kblk + (kb + 1) * 4096);
      const char* vs_ = (const char*)(vblk + (kb + 1) * 4096);
      char* db = (char*)KV[(kb + 1) & 1];
      gload_lds16(ks_ + tid * 16, db + wave * 1024);
      gload_lds16(ks_ + 4096 + tid * 16, db + 4096 + wave * 1024);
      gload_lds16(vs_ + tid * 16, db + 8192 + wave * 1024);
      gload_lds16(vs_ + 4096 + tid * 16, db + 12288 + wave * 1024);
    }

    // ---- S-MFMAs: mt0 then mt1 (kfa regs die before kfb loads -> low peak) ----
    f32x16 sA = fzero16(), sB = fzero16();
    {
      bf16x8 kf[4];
#pragma unroll
      for (int ks = 0; ks < 4; ++ks)
        kf[ks] = *(const bf16x8*)(Kc + ks * 512 + lane * 8);
      __builtin_amdgcn_s_setprio(1);
#pragma unroll
      for (int ks = 0; ks < 4; ++ks) sA = MFMA32(kf[ks], qf[ks], sA);
      __builtin_amdgcn_s_setprio(0);
    }
    {
      bf16x8 kf[4];
#pragma unroll
      for (int ks = 0; ks < 4; ++ks)
        kf[ks] = *(const bf16x8*)(Kc + 2048 + ks * 512 + lane * 8);
      __builtin_amdgcn_s_setprio(1);
#pragma unroll
      for (int ks = 0; ks < 4; ++ks) sB = MFMA32(kf[ks], qf[ks], sB);
      __builtin_amdgcn_s_setprio(0);
    }

    // V frags from LDS (issue early; land during ptrans)
    bf16x8 vf[2][4];
#pragma unroll
    for (int dt = 0; dt < 2; ++dt)
#pragma unroll
      for (int ks = 0; ks < 4; ++ks)
        vf[dt][ks] = *(const bf16x8*)(Vc + dt * 2048 + ks * 512 + lane * 8);

    // ---- ptrans mt0 -> PV mt0; ptrans mt1 overlaps PV mt0 drain ----
    bf16x8 fA0, fA1, fB0, fB1;
    ptrans(sA, rsum, fA0, fA1);
    __builtin_amdgcn_s_setprio(1);
    o[0] = MFMA32(vf[0][0], fA0, o[0]);
    o[1] = MFMA32(vf[1][0], fA0, o[1]);
    o[0] = MFMA32(vf[0][1], fA1, o[0]);
    o[1] = MFMA32(vf[1][1], fA1, o[1]);
    __builtin_amdgcn_s_setprio(0);
    ptrans(sB, rsum, fB0, fB1);
    __builtin_amdgcn_s_setprio(1);
    o[0] = MFMA32(vf[0][2], fB0, o[0]);
    o[1] = MFMA32(vf[1][2], fB0, o[1]);
    o[0] = MFMA32(vf[0][3], fB1, o[0]);
    o[1] = MFMA32(vf[1][3], fB1, o[1]);
    __builtin_amdgcn_s_setprio(0);

    // all reads of this buffer done; staged next buffer drained (vmcnt 0 in
    // __syncthreads) -> safe to swap
    __syncthreads();
  }

  // normalize + write bf16 chunk partial. O^T: d=dt*32+4*lh+8*g+t, q=l31
  unsigned short* cB = chunk ? c1 : c0;
  const int b = bh >> 4, h = bh & 15;
  float lsum = rsum + __shfl_xor(rsum, 32);
  float inv = 1.f / lsum;
  int s = q0 + l31;
#pragma unroll
  for (int dt = 0; dt < 2; ++dt)
#pragma unroll
    for (int g = 0; g < 4; ++g) {
      int d = dt * 32 + 4 * lh + 8 * g;
      size_t idx = ((size_t)(b * 2048 + s)) * 1024 + h * 64 + d;
      ushort4 hv;
#pragma unroll
      for (int t = 0; t < 4; ++t)
        ((unsigned short*)&hv)[t] = f2bf(o[dt][g * 4 + t] * inv);
      *(ushort4*)(cB + idx) = hv;
    }
}

// ---------------- K3b: combine chunk partials: attnB = bf16(c0 + c1) ----------------
__global__ __launch_bounds__(256) void k_comb(const unsigned short* __restrict__ c0,
                                              const unsigned short* __restrict__ c1,
                                              unsigned short* __restrict__ outB,
                                              int n8) {
  int i = blockIdx.x * blockDim.x + threadIdx.x;
  if (i >= n8) return;
  uint4 a = ((const uint4*)c0)[i];
  uint4 b = ((const uint4*)c1)[i];
  uint4 r;
  const unsigned short* pa = (const unsigned short*)&a;
  const unsigned short* pb = (const unsigned short*)&b;
  unsigned short* pr = (unsigned short*)&r;
#pragma unroll
  for (int j = 0; j < 8; ++j) pr[j] = f2bf(bf2f(pa[j]) + bf2f(pb[j]));
  ((uint4*)outB)[i] = r;
}

// ---------------- K4: output projection, plain bf16, fp32 store ----------------
__global__ __launch_bounds__(256, 2) void k_out(const unsigned short* __restrict__ A,
                                                const unsigned short* __restrict__ B,
                                                float* __restrict__ out) {
  __shared__ unsigned short Ah[128 * 32], Bh[128 * 32];
  const int tid = threadIdx.x;
  const int bm = blockIdx.y, n0 = blockIdx.x * 128;
  const int lane = tid & 63, wave = tid >> 6;
  const int wm = (wave & 1) * 64, wn = (wave >> 1) * 64;
  const int l15 = lane & 15, lq = lane >> 4;

  f32x4 acc[4][4];
#pragma unroll
  for (int i = 0; i < 4; i++)
#pragma unroll
    for (int j = 0; j < 4; j++) acc[i][j] = (f32x4){0.f, 0.f, 0.f, 0.f};

  const char* baseA = (const char*)A + (size_t)(bm * 128) * 2048;
  const char* baseB = (const char*)B + (size_t)n0 * 2048;
  const int off0 = tid << 4, row0 = off0 >> 6, seg0 = off0 & 63;
  const int off1 = (tid + 256) << 4, row1 = off1 >> 6, seg1 = off1 & 63;

  for (int k0 = 0; k0 < 1024; k0 += 32) {
    __syncthreads();
    gload_lds16(baseA + (size_t)row0 * 2048 + k0 * 2 + seg0, (char*)Ah + wave * 1024);
    gload_lds16(baseB + (size_t)row0 * 2048 + k0 * 2 + seg0, (char*)Bh + wave * 1024);
    gload_lds16(baseA + (size_t)row1 * 2048 + k0 * 2 + seg1,
                (char*)Ah + 4096 + wave * 1024);
    gload_lds16(baseB + (size_t)row1 * 2048 + k0 * 2 + seg1,
                (char*)Bh + 4096 + wave * 1024);
    __syncthreads();
    bf16x8 ah[4], bh[4];
#pragma unroll
    for (int i = 0; i < 4; ++i) {
      ah[i] = *(const bf16x8*)&Ah[(wm + i * 16 + l15) * 32 + lq * 8];
      bh[i] = *(const bf16x8*)&Bh[(wn + i * 16 + l15) * 32 + lq * 8];
    }
#pragma unroll
    for (int i = 0; i < 4; ++i)
#pragma unroll
      for (int j = 0; j < 4; ++j) acc[i][j] = MFMA16(ah[i], bh[j], acc[i][j]);
  }
#pragma unroll
  for (int i = 0; i < 4; ++i)
#pragma unroll
    for (int j = 0; j < 4; ++j) {
      int colw = n0 + wn + j * 16 + l15;
#pragma unroll
      for (int r = 0; r < 4; ++r) {
        int rowg = bm * 128 + wm + i * 16 + lq * 4 + r;
        out[(size_t)rowg * 1024 + colw] = acc[i][j][r];
      }
    }
}

// ---------------- launch ----------------
extern "C" void kernel_launch(void* const* d_in, const int* in_sizes, int n_in,
                              void* d_out, int out_size, void* d_ws, size_t ws_size,
                              hipStream_t stream) {
  const float* hs = (const float*)d_in[0];
  const float* freqs = (const float*)d_in[1];
  const float* Wq = (const float*)d_in[2];
  const float* Wk = (const float*)d_in[3];
  const float* Wv = (const float*)d_in[4];
  const float* Wo = (const float*)d_in[5];
  float* out = (float*)d_out;

  const size_t MD = (size_t)4096 * 1024;
  const size_t WW = (size_t)1024 * 1024;
  unsigned short* hsH = (unsigned short*)d_ws;   // 8MB; reused as attnB
  unsigned short* WtqH = hsH + MD;
  unsigned short* WtkH = WtqH + WW;
  unsigned short* WtvH = WtkH + WW;
  unsigned short* WtoH = WtvH + WW;
  unsigned short* qB = WtoH + WW;
  unsigned short* kB = qB + MD;
  unsigned short* vB = kB + MD;
  unsigned short* c0 = vB + MD;
  unsigned short* c1 = c0 + MD;
  unsigned short* attnB = hsH;  // hs bf16 dead after k_qkv

  k_split<<<4096, 256, 0, stream>>>(hs, hsH, (int)(MD / 4));
  k_wsplit<<<dim3(32, 32, 4), 256, 0, stream>>>(Wq, Wk, Wv, Wo,
                                                WtqH, WtkH, WtvH, WtoH);
  k_qkv<<<dim3(24, 32), 256, 0, stream>>>(hsH, WtqH, WtkH, WtvH, freqs, qB, kB, vB);
  k_attn<<<1024, 256, 0, stream>>>(qB, kB, vB, c0, c1);
  k_comb<<<2048, 256, 0, stream>>>(c0, c1, attnB, (int)(MD / 8));
  k_out<<<dim3(8, 32), 256, 0, stream>>>(attnB, WtoH, out);
}

// Round 10
// 213.175 us; speedup vs baseline: 1.0133x; 1.0133x over previous
//
#include <hip/hip_runtime.h>
#include <hip/hip_bf16.h>
#include <cstdint>

typedef __bf16 bf16x8 __attribute__((ext_vector_type(8)));
typedef float f32x4 __attribute__((ext_vector_type(4)));
typedef float f32x16 __attribute__((ext_vector_type(16)));

#define MFMA16(a, b, c) __builtin_amdgcn_mfma_f32_16x16x32_bf16(a, b, c, 0, 0, 0)
#define MFMA32(a, b, c) __builtin_amdgcn_mfma_f32_32x32x16_bf16(a, b, c, 0, 0, 0)

__device__ __forceinline__ void gload_lds16(const void* g, void* l) {
  __builtin_amdgcn_global_load_lds(
      (const __attribute__((address_space(1))) unsigned int*)g,
      (__attribute__((address_space(3))) unsigned int*)l, 16, 0, 0);
}

__device__ __forceinline__ unsigned short f2bf(float x) {
  union { float f; uint32_t u; } v; v.f = x;
  uint32_t r = v.u + 0x7fff + ((v.u >> 16) & 1);
  return (unsigned short)(r >> 16);
}
__device__ __forceinline__ float bf2f(unsigned short h) {
  union { float f; uint32_t u; } v; v.u = ((uint32_t)h) << 16;
  return v.f;
}
__device__ __forceinline__ f32x16 fzero16() {
  f32x16 v;
#pragma unroll
  for (int i = 0; i < 16; ++i) v[i] = 0.f;
  return v;
}

// S-tile (f32x16, pre-scaled by sc*log2e via Q) -> exp2 -> two PV B-frags.
// ZERO cross-lane ops (V stored with matching key permutation in k_qkv).
__device__ __forceinline__ void ptrans(const f32x16& sv, float& rsum,
                                       bf16x8& f0, bf16x8& f1) {
  float ps[16];
#pragma unroll
  for (int r = 0; r < 16; ++r) ps[r] = __builtin_exp2f(sv[r]);
  float rs = 0.f;
#pragma unroll
  for (int r = 0; r < 16; ++r) rs += ps[r];
  rsum += rs;
  bf16x8 a, b;
#pragma unroll
  for (int r = 0; r < 8; ++r) a[r] = (__bf16)ps[r];
#pragma unroll
  for (int r = 0; r < 8; ++r) b[r] = (__bf16)ps[8 + r];
  f0 = a; f1 = b;
}

// ---------------- K1a: hidden_states -> bf16 ----------------
__global__ __launch_bounds__(256) void k_split(const float* __restrict__ x,
                                               unsigned short* __restrict__ hi, int n4) {
  int i = blockIdx.x * blockDim.x + threadIdx.x;
  if (i >= n4) return;
  float4 v = ((const float4*)x)[i];
  ushort4 h;
  h.x = f2bf(v.x); h.y = f2bf(v.y); h.z = f2bf(v.z); h.w = f2bf(v.w);
  ((ushort4*)hi)[i] = h;
}

// ------------ K1b: transpose weights -> bf16 (fused, z selects W) ------------
__global__ __launch_bounds__(256) void k_wsplit(
    const float* __restrict__ Wq, const float* __restrict__ Wk,
    const float* __restrict__ Wv, const float* __restrict__ Wo,
    unsigned short* __restrict__ WtqH, unsigned short* __restrict__ WtkH,
    unsigned short* __restrict__ WtvH, unsigned short* __restrict__ WtoH) {
  const int z = blockIdx.z;
  const float* W = (z == 0) ? Wq : (z == 1) ? Wk : (z == 2) ? Wv : Wo;
  unsigned short* WtH = (z == 0) ? WtqH : (z == 1) ? WtkH : (z == 2) ? WtvH : WtoH;
  __shared__ float tile[32][33];
  const int bx = blockIdx.x, by = blockIdx.y;
  const int tx = threadIdx.x & 31, ty = threadIdx.x >> 5;
#pragma unroll
  for (int i = 0; i < 4; ++i)
    tile[ty + i * 8][tx] = W[(size_t)(by * 32 + ty + i * 8) * 1024 + bx * 32 + tx];
  __syncthreads();
#pragma unroll
  for (int i = 0; i < 4; ++i) {
    float v = tile[tx][ty + i * 8];
    WtH[(size_t)(bx * 32 + ty + i * 8) * 1024 + by * 32 + tx] = f2bf(v);
  }
}

// ---------------- K2: QKV GEMM, plain bf16, global_load_lds staging ----------------
// K and V stored FRAG-LINEAR (see round 7): per 64-key kb-block the 8KB region
// is contiguous -> k_attn stages each kb-block with 4 coalesced global_load_lds.
__global__ __launch_bounds__(256, 2) void k_qkv(
    const unsigned short* __restrict__ hsH,
    const unsigned short* __restrict__ WqH, const unsigned short* __restrict__ WkH,
    const unsigned short* __restrict__ WvH, const float* __restrict__ freqs,
    unsigned short* __restrict__ qB, unsigned short* __restrict__ kB,
    unsigned short* __restrict__ vB) {
  __shared__ unsigned short Ah[128 * 32], Bh[128 * 32];  // 8KB each, 64B rows
  const int tid = threadIdx.x;
  const int bm = blockIdx.y, bn = blockIdx.x;
  const int w = bn >> 3;           // 0=q 1=k 2=v
  const int n0 = (bn & 7) * 128;
  const unsigned short* WH = (w == 0) ? WqH : (w == 1) ? WkH : WvH;
  const int lane = tid & 63, wave = tid >> 6;
  const int wm = (wave & 1) * 64, wn = (wave >> 1) * 64;
  const int l15 = lane & 15, lq = lane >> 4;

  f32x4 acc[4][4];
#pragma unroll
  for (int i = 0; i < 4; i++)
#pragma unroll
    for (int j = 0; j < 4; j++) acc[i][j] = (f32x4){0.f, 0.f, 0.f, 0.f};

  const char* baseA = (const char*)hsH + (size_t)(bm * 128) * 2048;
  const char* baseB = (const char*)WH + (size_t)n0 * 2048;
  const int off0 = tid << 4, row0 = off0 >> 6, seg0 = off0 & 63;
  const int off1 = (tid + 256) << 4, row1 = off1 >> 6, seg1 = off1 & 63;

  for (int k0 = 0; k0 < 1024; k0 += 32) {
    __syncthreads();
    gload_lds16(baseA + (size_t)row0 * 2048 + k0 * 2 + seg0, (char*)Ah + wave * 1024);
    gload_lds16(baseB + (size_t)row0 * 2048 + k0 * 2 + seg0, (char*)Bh + wave * 1024);
    gload_lds16(baseA + (size_t)row1 * 2048 + k0 * 2 + seg1,
                (char*)Ah + 4096 + wave * 1024);
    gload_lds16(baseB + (size_t)row1 * 2048 + k0 * 2 + seg1,
                (char*)Bh + 4096 + wave * 1024);
    __syncthreads();
    bf16x8 ah[4], bh[4];
#pragma unroll
    for (int i = 0; i < 4; ++i) {
      ah[i] = *(const bf16x8*)&Ah[(wm + i * 16 + l15) * 32 + lq * 8];
      bh[i] = *(const bf16x8*)&Bh[(wn + i * 16 + l15) * 32 + lq * 8];
    }
#pragma unroll
    for (int i = 0; i < 4; ++i)
#pragma unroll
      for (int j = 0; j < 4; ++j) acc[i][j] = MFMA16(ah[i], bh[j], acc[i][j]);
  }

  // epilogue: C/D layout col=lane&15, row=(lane>>4)*4+r. RoPE for q,k.
  // Softmax scale * log2(e) folded into Q (f32, commutes with RoPE rotation).
  unsigned short* dst = (w == 0) ? qB : (w == 1) ? kB : vB;
#pragma unroll
  for (int i = 0; i < 4; ++i) {
#pragma unroll
    for (int j = 0; j < 4; ++j) {
      int colw = n0 + wn + j * 16 + l15;
      int h = colw >> 6, d = colw & 63;
#pragma unroll
      for (int r = 0; r < 4; ++r) {
        int rowg = bm * 128 + wm + i * 16 + lq * 4 + r;
        int s = rowg & 2047, b = rowg >> 11;
        float val = acc[i][j][r];
        size_t bhb = (size_t)(b * 16 + h) * 131072;
        if (w < 2) {
          float partner = __shfl_xor(val, 1);
          int jj = d >> 1;
          float2 cssn = ((const float2*)freqs)[s * 32 + jj];
          float cs = cssn.x, sn = cssn.y;
          float res = (d & 1) ? (partner * sn + val * cs) : (val * cs - partner * sn);
          if (w == 0) {
            res *= 0.18033688011112042f;  // 0.125 * log2(e)
            dst[(((size_t)(b * 16 + h)) * 2048 + s) * 64 + d] = f2bf(res);
          } else {
            size_t off = (size_t)(s >> 10) * 65536 + ((s >> 6) & 15) * 4096 +
                         ((s >> 5) & 1) * 2048 + (d >> 4) * 512 +
                         ((s & 31) + 32 * ((d >> 3) & 1)) * 8 + (d & 7);
            dst[bhb + off] = f2bf(res);
          }
        } else {
          // key permutation within 16-groups (swap middle 4-blocks)
          int sp = (s & ~12) | ((s & 4) << 1) | ((s & 8) >> 1);
          size_t off = (size_t)(sp >> 10) * 65536 + ((sp >> 6) & 15) * 4096 +
                       (d >> 5) * 2048 + ((sp >> 4) & 3) * 512 +
                       ((d & 31) + 32 * ((sp >> 3) & 1)) * 8 + (sp & 7);
          dst[bhb + off] = f2bf(val);
        }
      }
    }
  }
}

// ------- K3: chunked attention, LDS-staged K/V + q-split: 4 blocks/CU -------
// (unchanged from round 9: VGPR=64, occupancy ~27%, 57.4us)
__global__ __launch_bounds__(256, 4) void k_attn(
    const unsigned short* __restrict__ qB, const unsigned short* __restrict__ kB,
    const unsigned short* __restrict__ vB,
    unsigned short* __restrict__ c0, unsigned short* __restrict__ c1) {
  __shared__ unsigned short KV[2][8192];  // [buf][K 4096 | V 4096] = 16KB/buf
  const int tid = threadIdx.x, lane = tid & 63, wave = tid >> 6;
  const int l31 = lane & 31, lh = lane >> 5;
  const int bid = blockIdx.x;
  const int x = (bid >> 3) & 15;
  const int gg = (bid & 7) + 8 * (bid >> 7);
  const int bh = gg & 31;
  const int chunk = gg >> 5;
  const int q0 = x * 128 + wave * 32;
  const size_t base = (size_t)bh * 131072;

  // Q B-frags (pre-scaled in k_qkv): lane n=l31 -> query q0+l31, k=ks*16+lh*8
  bf16x8 qf[4];
#pragma unroll
  for (int ks = 0; ks < 4; ++ks)
    qf[ks] = *(const bf16x8*)(qB + base + (size_t)(q0 + l31) * 64 + ks * 16 + lh * 8);

  const unsigned short* kblk = kB + base + chunk * 65536;  // + kb*4096 elems (8KB)
  const unsigned short* vblk = vB + base + chunk * 65536;

  // prologue: stage kb=0 into buf 0
  gload_lds16((const char*)kblk + tid * 16, (char*)KV[0] + wave * 1024);
  gload_lds16((const char*)kblk + 4096 + tid * 16, (char*)KV[0] + 4096 + wave * 1024);
  gload_lds16((const char*)vblk + tid * 16, (char*)KV[0] + 8192 + wave * 1024);
  gload_lds16((const char*)vblk + 4096 + tid * 16, (char*)KV[0] + 12288 + wave * 1024);
  __syncthreads();

  f32x16 o[2];  // [dt]
#pragma unroll
  for (int a = 0; a < 2; ++a) o[a] = fzero16();
  float rsum = 0.f;

  for (int kb = 0; kb < 16; ++kb) {
    const unsigned short* Kc = KV[kb & 1];
    const unsigned short* Vc = KV[kb & 1] + 4096;
    // stage kb+1 into the other buffer (loads in flight across the compute)
    if (kb < 15) {
      const char* ks_ = (const char*)(kblk + (kb + 1) * 4096);
      const char* vs_ = (const char*)(vblk + (kb + 1) * 4096);
      char* db = (char*)KV[(kb + 1) & 1];
      gload_lds16(ks_ + tid * 16, db + wave * 1024);
      gload_lds16(ks_ + 4096 + tid * 16, db + 4096 + wave * 1024);
      gload_lds16(vs_ + tid * 16, db + 8192 + wave * 1024);
      gload_lds16(vs_ + 4096 + tid * 16, db + 12288 + wave * 1024);
    }

    // ---- S-MFMAs: mt0 then mt1 (kfa regs die before kfb loads -> low peak) ----
    f32x16 sA = fzero16(), sB = fzero16();
    {
      bf16x8 kf[4];
#pragma unroll
      for (int ks = 0; ks < 4; ++ks)
        kf[ks] = *(const bf16x8*)(Kc + ks * 512 + lane * 8);
      __builtin_amdgcn_s_setprio(1);
#pragma unroll
      for (int ks = 0; ks < 4; ++ks) sA = MFMA32(kf[ks], qf[ks], sA);
      __builtin_amdgcn_s_setprio(0);
    }
    {
      bf16x8 kf[4];
#pragma unroll
      for (int ks = 0; ks < 4; ++ks)
        kf[ks] = *(const bf16x8*)(Kc + 2048 + ks * 512 + lane * 8);
      __builtin_amdgcn_s_setprio(1);
#pragma unroll
      for (int ks = 0; ks < 4; ++ks) sB = MFMA32(kf[ks], qf[ks], sB);
      __builtin_amdgcn_s_setprio(0);
    }

    // V frags from LDS (issue early; land during ptrans)
    bf16x8 vf[2][4];
#pragma unroll
    for (int dt = 0; dt < 2; ++dt)
#pragma unroll
      for (int ks = 0; ks < 4; ++ks)
        vf[dt][ks] = *(const bf16x8*)(Vc + dt * 2048 + ks * 512 + lane * 8);

    // ---- ptrans mt0 -> PV mt0; ptrans mt1 overlaps PV mt0 drain ----
    bf16x8 fA0, fA1, fB0, fB1;
    ptrans(sA, rsum, fA0, fA1);
    __builtin_amdgcn_s_setprio(1);
    o[0] = MFMA32(vf[0][0], fA0, o[0]);
    o[1] = MFMA32(vf[1][0], fA0, o[1]);
    o[0] = MFMA32(vf[0][1], fA1, o[0]);
    o[1] = MFMA32(vf[1][1], fA1, o[1]);
    __builtin_amdgcn_s_setprio(0);
    ptrans(sB, rsum, fB0, fB1);
    __builtin_amdgcn_s_setprio(1);
    o[0] = MFMA32(vf[0][2], fB0, o[0]);
    o[1] = MFMA32(vf[1][2], fB0, o[1]);
    o[0] = MFMA32(vf[0][3], fB1, o[0]);
    o[1] = MFMA32(vf[1][3], fB1, o[1]);
    __builtin_amdgcn_s_setprio(0);

    // all reads of this buffer done; staged next buffer drained (vmcnt 0 in
    // __syncthreads) -> safe to swap
    __syncthreads();
  }

  // normalize + write bf16 chunk partial. O^T: d=dt*32+4*lh+8*g+t, q=l31
  unsigned short* cB = chunk ? c1 : c0;
  const int b = bh >> 4, h = bh & 15;
  float lsum = rsum + __shfl_xor(rsum, 32);
  float inv = 1.f / lsum;
  int s = q0 + l31;
#pragma unroll
  for (int dt = 0; dt < 2; ++dt)
#pragma unroll
    for (int g = 0; g < 4; ++g) {
      int d = dt * 32 + 4 * lh + 8 * g;
      size_t idx = ((size_t)(b * 2048 + s)) * 1024 + h * 64 + d;
      ushort4 hv;
#pragma unroll
      for (int t = 0; t < 4; ++t)
        ((unsigned short*)&hv)[t] = f2bf(o[dt][g * 4 + t] * inv);
      *(ushort4*)(cB + idx) = hv;
    }
}

// ---------------- K3b: combine chunk partials: attnB = bf16(c0 + c1) ----------------
__global__ __launch_bounds__(256) void k_comb(const unsigned short* __restrict__ c0,
                                              const unsigned short* __restrict__ c1,
                                              unsigned short* __restrict__ outB,
                                              int n8) {
  int i = blockIdx.x * blockDim.x + threadIdx.x;
  if (i >= n8) return;
  uint4 a = ((const uint4*)c0)[i];
  uint4 b = ((const uint4*)c1)[i];
  uint4 r;
  const unsigned short* pa = (const unsigned short*)&a;
  const unsigned short* pb = (const unsigned short*)&b;
  unsigned short* pr = (unsigned short*)&r;
#pragma unroll
  for (int j = 0; j < 8; ++j) pr[j] = f2bf(bf2f(pa[j]) + bf2f(pb[j]));
  ((uint4*)outB)[i] = r;
}

// ---------------- K4: output projection, 128x64 tiles for 2 blocks/CU ----------------
// Round-9 diagnosis: grid (8,32)=256 blocks = exactly 1 block/CU = 4 waves/CU
// (12.5% occupancy cap) -- the barrier drain per k-step had no other block to
// overlap with. 128x64 tiles -> grid (16,32)=512 blocks = 2/CU, 8 waves/CU.
// Per wave: 64x32 output (acc[4][2]), 8 MFMA16/k-step. LDS 12KB (A 8KB, B 4KB).
__global__ __launch_bounds__(256, 2) void k_out(const unsigned short* __restrict__ A,
                                                const unsigned short* __restrict__ B,
                                                float* __restrict__ out) {
  __shared__ unsigned short Ah[128 * 32], Bh[64 * 32];  // 8KB, 4KB
  const int tid = threadIdx.x;
  const int bm = blockIdx.y, n0 = blockIdx.x * 64;
  const int lane = tid & 63, wave = tid >> 6;
  const int wm = (wave & 1) * 64, wn = (wave >> 1) * 32;
  const int l15 = lane & 15, lq = lane >> 4;

  f32x4 acc[4][2];
#pragma unroll
  for (int i = 0; i < 4; i++)
#pragma unroll
    for (int j = 0; j < 2; j++) acc[i][j] = (f32x4){0.f, 0.f, 0.f, 0.f};

  const char* baseA = (const char*)A + (size_t)(bm * 128) * 2048;
  const char* baseB = (const char*)B + (size_t)n0 * 2048;
  const int off0 = tid << 4, row0 = off0 >> 6, seg0 = off0 & 63;
  const int off1 = (tid + 256) << 4, row1 = off1 >> 6, seg1 = off1 & 63;

  for (int k0 = 0; k0 < 1024; k0 += 32) {
    __syncthreads();
    gload_lds16(baseA + (size_t)row0 * 2048 + k0 * 2 + seg0, (char*)Ah + wave * 1024);
    gload_lds16(baseA + (size_t)row1 * 2048 + k0 * 2 + seg1,
                (char*)Ah + 4096 + wave * 1024);
    gload_lds16(baseB + (size_t)row0 * 2048 + k0 * 2 + seg0, (char*)Bh + wave * 1024);
    __syncthreads();
    bf16x8 ah[4], bh[2];
#pragma unroll
    for (int i = 0; i < 4; ++i)
      ah[i] = *(const bf16x8*)&Ah[(wm + i * 16 + l15) * 32 + lq * 8];
#pragma unroll
    for (int j = 0; j < 2; ++j)
      bh[j] = *(const bf16x8*)&Bh[(wn + j * 16 + l15) * 32 + lq * 8];
#pragma unroll
    for (int i = 0; i < 4; ++i)
#pragma unroll
      for (int j = 0; j < 2; ++j) acc[i][j] = MFMA16(ah[i], bh[j], acc[i][j]);
  }
#pragma unroll
  for (int i = 0; i < 4; ++i)
#pragma unroll
    for (int j = 0; j < 2; ++j) {
      int colw = n0 + wn + j * 16 + l15;
#pragma unroll
      for (int r = 0; r < 4; ++r) {
        int rowg = bm * 128 + wm + i * 16 + lq * 4 + r;
        out[(size_t)rowg * 1024 + colw] = acc[i][j][r];
      }
    }
}

// ---------------- launch ----------------
extern "C" void kernel_launch(void* const* d_in, const int* in_sizes, int n_in,
                              void* d_out, int out_size, void* d_ws, size_t ws_size,
                              hipStream_t stream) {
  const float* hs = (const float*)d_in[0];
  const float* freqs = (const float*)d_in[1];
  const float* Wq = (const float*)d_in[2];
  const float* Wk = (const float*)d_in[3];
  const float* Wv = (const float*)d_in[4];
  const float* Wo = (const float*)d_in[5];
  float* out = (float*)d_out;

  const size_t MD = (size_t)4096 * 1024;
  const size_t WW = (size_t)1024 * 1024;
  unsigned short* hsH = (unsigned short*)d_ws;   // 8MB; reused as attnB
  unsigned short* WtqH = hsH + MD;
  unsigned short* WtkH = WtqH + WW;
  unsigned short* WtvH = WtkH + WW;
  unsigned short* WtoH = WtvH + WW;
  unsigned short* qB = WtoH + WW;
  unsigned short* kB = qB + MD;
  unsigned short* vB = kB + MD;
  unsigned short* c0 = vB + MD;
  unsigned short* c1 = c0 + MD;
  unsigned short* attnB = hsH;  // hs bf16 dead after k_qkv

  k_split<<<4096, 256, 0, stream>>>(hs, hsH, (int)(MD / 4));
  k_wsplit<<<dim3(32, 32, 4), 256, 0, stream>>>(Wq, Wk, Wv, Wo,
                                                WtqH, WtkH, WtvH, WtoH);
  k_qkv<<<dim3(24, 32), 256, 0, stream>>>(hsH, WtqH, WtkH, WtvH, freqs, qB, kB, vB);
  k_attn<<<1024, 256, 0, stream>>>(qB, kB, vB, c0, c1);
  k_comb<<<2048, 256, 0, stream>>>(c0, c1, attnB, (int)(MD / 8));
  k_out<<<dim3(16, 32), 256, 0, stream>>>(attnB, WtoH, out);
}

// Round 11
// 208.892 us; speedup vs baseline: 1.0340x; 1.0205x over previous
//
#include <hip/hip_runtime.h>
#include <hip/hip_bf16.h>
#include <cstdint>

typedef __bf16 bf16x8 __attribute__((ext_vector_type(8)));
typedef float f32x4 __attribute__((ext_vector_type(4)));
typedef float f32x16 __attribute__((ext_vector_type(16)));

#define MFMA16(a, b, c) __builtin_amdgcn_mfma_f32_16x16x32_bf16(a, b, c, 0, 0, 0)
#define MFMA32(a, b, c) __builtin_amdgcn_mfma_f32_32x32x16_bf16(a, b, c, 0, 0, 0)

__device__ __forceinline__ void gload_lds16(const void* g, void* l) {
  __builtin_amdgcn_global_load_lds(
      (const __attribute__((address_space(1))) unsigned int*)g,
      (__attribute__((address_space(3))) unsigned int*)l, 16, 0, 0);
}

__device__ __forceinline__ unsigned short f2bf(float x) {
  union { float f; uint32_t u; } v; v.f = x;
  uint32_t r = v.u + 0x7fff + ((v.u >> 16) & 1);
  return (unsigned short)(r >> 16);
}
__device__ __forceinline__ float bf2f(unsigned short h) {
  union { float f; uint32_t u; } v; v.u = ((uint32_t)h) << 16;
  return v.f;
}
__device__ __forceinline__ f32x16 fzero16() {
  f32x16 v;
#pragma unroll
  for (int i = 0; i < 16; ++i) v[i] = 0.f;
  return v;
}

// S-tile (f32x16, pre-scaled by sc*log2e via Q) -> exp2 -> two PV B-frags.
// ZERO cross-lane ops (V stored with matching key permutation in k_qkv).
__device__ __forceinline__ void ptrans(const f32x16& sv, float& rsum,
                                       bf16x8& f0, bf16x8& f1) {
  float ps[16];
#pragma unroll
  for (int r = 0; r < 16; ++r) ps[r] = __builtin_exp2f(sv[r]);
  float rs = 0.f;
#pragma unroll
  for (int r = 0; r < 16; ++r) rs += ps[r];
  rsum += rs;
  bf16x8 a, b;
#pragma unroll
  for (int r = 0; r < 8; ++r) a[r] = (__bf16)ps[r];
#pragma unroll
  for (int r = 0; r < 8; ++r) b[r] = (__bf16)ps[8 + r];
  f0 = a; f1 = b;
}

// ---------------- K1a: hidden_states -> bf16 ----------------
__global__ __launch_bounds__(256) void k_split(const float* __restrict__ x,
                                               unsigned short* __restrict__ hi, int n4) {
  int i = blockIdx.x * blockDim.x + threadIdx.x;
  if (i >= n4) return;
  float4 v = ((const float4*)x)[i];
  ushort4 h;
  h.x = f2bf(v.x); h.y = f2bf(v.y); h.z = f2bf(v.z); h.w = f2bf(v.w);
  ((ushort4*)hi)[i] = h;
}

// ------------ K1b: transpose weights -> bf16 (fused, z selects W) ------------
__global__ __launch_bounds__(256) void k_wsplit(
    const float* __restrict__ Wq, const float* __restrict__ Wk,
    const float* __restrict__ Wv, const float* __restrict__ Wo,
    unsigned short* __restrict__ WtqH, unsigned short* __restrict__ WtkH,
    unsigned short* __restrict__ WtvH, unsigned short* __restrict__ WtoH) {
  const int z = blockIdx.z;
  const float* W = (z == 0) ? Wq : (z == 1) ? Wk : (z == 2) ? Wv : Wo;
  unsigned short* WtH = (z == 0) ? WtqH : (z == 1) ? WtkH : (z == 2) ? WtvH : WtoH;
  __shared__ float tile[32][33];
  const int bx = blockIdx.x, by = blockIdx.y;
  const int tx = threadIdx.x & 31, ty = threadIdx.x >> 5;
#pragma unroll
  for (int i = 0; i < 4; ++i)
    tile[ty + i * 8][tx] = W[(size_t)(by * 32 + ty + i * 8) * 1024 + bx * 32 + tx];
  __syncthreads();
#pragma unroll
  for (int i = 0; i < 4; ++i) {
    float v = tile[tx][ty + i * 8];
    WtH[(size_t)(bx * 32 + ty + i * 8) * 1024 + by * 32 + tx] = f2bf(v);
  }
}

// ---------------- K2: QKV GEMM, plain bf16, global_load_lds staging ----------------
// K and V stored FRAG-LINEAR (see round 7): per 64-key kb-block the 8KB region
// is contiguous -> k_attn stages each kb-block with 4 coalesced global_load_lds.
// launch_bounds (256,3): grid (24,32)=768 blocks = exactly 3/CU. The previous
// (256,2) capped residency at 2 -> a full 512-block pass plus a half-idle
// 256-block tail (~1.5x single-pass time). Unified reg usage ~124/wave fits
// the (256,3) cap of ~170 with margin (round-4 spill mode: usage > cap).
__global__ __launch_bounds__(256, 3) void k_qkv(
    const unsigned short* __restrict__ hsH,
    const unsigned short* __restrict__ WqH, const unsigned short* __restrict__ WkH,
    const unsigned short* __restrict__ WvH, const float* __restrict__ freqs,
    unsigned short* __restrict__ qB, unsigned short* __restrict__ kB,
    unsigned short* __restrict__ vB) {
  __shared__ unsigned short Ah[128 * 32], Bh[128 * 32];  // 8KB each, 64B rows
  const int tid = threadIdx.x;
  const int bm = blockIdx.y, bn = blockIdx.x;
  const int w = bn >> 3;           // 0=q 1=k 2=v
  const int n0 = (bn & 7) * 128;
  const unsigned short* WH = (w == 0) ? WqH : (w == 1) ? WkH : WvH;
  const int lane = tid & 63, wave = tid >> 6;
  const int wm = (wave & 1) * 64, wn = (wave >> 1) * 64;
  const int l15 = lane & 15, lq = lane >> 4;

  f32x4 acc[4][4];
#pragma unroll
  for (int i = 0; i < 4; i++)
#pragma unroll
    for (int j = 0; j < 4; j++) acc[i][j] = (f32x4){0.f, 0.f, 0.f, 0.f};

  const char* baseA = (const char*)hsH + (size_t)(bm * 128) * 2048;
  const char* baseB = (const char*)WH + (size_t)n0 * 2048;
  const int off0 = tid << 4, row0 = off0 >> 6, seg0 = off0 & 63;
  const int off1 = (tid + 256) << 4, row1 = off1 >> 6, seg1 = off1 & 63;

  for (int k0 = 0; k0 < 1024; k0 += 32) {
    __syncthreads();
    gload_lds16(baseA + (size_t)row0 * 2048 + k0 * 2 + seg0, (char*)Ah + wave * 1024);
    gload_lds16(baseB + (size_t)row0 * 2048 + k0 * 2 + seg0, (char*)Bh + wave * 1024);
    gload_lds16(baseA + (size_t)row1 * 2048 + k0 * 2 + seg1,
                (char*)Ah + 4096 + wave * 1024);
    gload_lds16(baseB + (size_t)row1 * 2048 + k0 * 2 + seg1,
                (char*)Bh + 4096 + wave * 1024);
    __syncthreads();
    bf16x8 ah[4], bh[4];
#pragma unroll
    for (int i = 0; i < 4; ++i) {
      ah[i] = *(const bf16x8*)&Ah[(wm + i * 16 + l15) * 32 + lq * 8];
      bh[i] = *(const bf16x8*)&Bh[(wn + i * 16 + l15) * 32 + lq * 8];
    }
#pragma unroll
    for (int i = 0; i < 4; ++i)
#pragma unroll
      for (int j = 0; j < 4; ++j) acc[i][j] = MFMA16(ah[i], bh[j], acc[i][j]);
  }

  // epilogue: C/D layout col=lane&15, row=(lane>>4)*4+r. RoPE for q,k.
  // Softmax scale * log2(e) folded into Q (f32, commutes with RoPE rotation).
  unsigned short* dst = (w == 0) ? qB : (w == 1) ? kB : vB;
#pragma unroll
  for (int i = 0; i < 4; ++i) {
#pragma unroll
    for (int j = 0; j < 4; ++j) {
      int colw = n0 + wn + j * 16 + l15;
      int h = colw >> 6, d = colw & 63;
#pragma unroll
      for (int r = 0; r < 4; ++r) {
        int rowg = bm * 128 + wm + i * 16 + lq * 4 + r;
        int s = rowg & 2047, b = rowg >> 11;
        float val = acc[i][j][r];
        size_t bhb = (size_t)(b * 16 + h) * 131072;
        if (w < 2) {
          float partner = __shfl_xor(val, 1);
          int jj = d >> 1;
          float2 cssn = ((const float2*)freqs)[s * 32 + jj];
          float cs = cssn.x, sn = cssn.y;
          float res = (d & 1) ? (partner * sn + val * cs) : (val * cs - partner * sn);
          if (w == 0) {
            res *= 0.18033688011112042f;  // 0.125 * log2(e)
            dst[(((size_t)(b * 16 + h)) * 2048 + s) * 64 + d] = f2bf(res);
          } else {
            size_t off = (size_t)(s >> 10) * 65536 + ((s >> 6) & 15) * 4096 +
                         ((s >> 5) & 1) * 2048 + (d >> 4) * 512 +
                         ((s & 31) + 32 * ((d >> 3) & 1)) * 8 + (d & 7);
            dst[bhb + off] = f2bf(res);
          }
        } else {
          // key permutation within 16-groups (swap middle 4-blocks)
          int sp = (s & ~12) | ((s & 4) << 1) | ((s & 8) >> 1);
          size_t off = (size_t)(sp >> 10) * 65536 + ((sp >> 6) & 15) * 4096 +
                       (d >> 5) * 2048 + ((sp >> 4) & 3) * 512 +
                       ((d & 31) + 32 * ((sp >> 3) & 1)) * 8 + (sp & 7);
          dst[bhb + off] = f2bf(val);
        }
      }
    }
  }
}

// ------- K3: chunked attention, LDS-staged K/V + q-split: 4 blocks/CU -------
// (unchanged from round 9: VGPR=64, occupancy ~27%, ~58us, 587 TF)
__global__ __launch_bounds__(256, 4) void k_attn(
    const unsigned short* __restrict__ qB, const unsigned short* __restrict__ kB,
    const unsigned short* __restrict__ vB,
    unsigned short* __restrict__ c0, unsigned short* __restrict__ c1) {
  __shared__ unsigned short KV[2][8192];  // [buf][K 4096 | V 4096] = 16KB/buf
  const int tid = threadIdx.x, lane = tid & 63, wave = tid >> 6;
  const int l31 = lane & 31, lh = lane >> 5;
  const int bid = blockIdx.x;
  const int x = (bid >> 3) & 15;
  const int gg = (bid & 7) + 8 * (bid >> 7);
  const int bh = gg & 31;
  const int chunk = gg >> 5;
  const int q0 = x * 128 + wave * 32;
  const size_t base = (size_t)bh * 131072;

  // Q B-frags (pre-scaled in k_qkv): lane n=l31 -> query q0+l31, k=ks*16+lh*8
  bf16x8 qf[4];
#pragma unroll
  for (int ks = 0; ks < 4; ++ks)
    qf[ks] = *(const bf16x8*)(qB + base + (size_t)(q0 + l31) * 64 + ks * 16 + lh * 8);

  const unsigned short* kblk = kB + base + chunk * 65536;  // + kb*4096 elems (8KB)
  const unsigned short* vblk = vB + base + chunk * 65536;

  // prologue: stage kb=0 into buf 0
  gload_lds16((const char*)kblk + tid * 16, (char*)KV[0] + wave * 1024);
  gload_lds16((const char*)kblk + 4096 + tid * 16, (char*)KV[0] + 4096 + wave * 1024);
  gload_lds16((const char*)vblk + tid * 16, (char*)KV[0] + 8192 + wave * 1024);
  gload_lds16((const char*)vblk + 4096 + tid * 16, (char*)KV[0] + 12288 + wave * 1024);
  __syncthreads();

  f32x16 o[2];  // [dt]
#pragma unroll
  for (int a = 0; a < 2; ++a) o[a] = fzero16();
  float rsum = 0.f;

  for (int kb = 0; kb < 16; ++kb) {
    const unsigned short* Kc = KV[kb & 1];
    const unsigned short* Vc = KV[kb & 1] + 4096;
    // stage kb+1 into the other buffer (loads in flight across the compute)
    if (kb < 15) {
      const char* ks_ = (const char*)(kblk + (kb + 1) * 4096);
      const char* vs_ = (const char*)(vblk + (kb + 1) * 4096);
      char* db = (char*)KV[(kb + 1) & 1];
      gload_lds16(ks_ + tid * 16, db + wave * 1024);
      gload_lds16(ks_ + 4096 + tid * 16, db + 4096 + wave * 1024);
      gload_lds16(vs_ + tid * 16, db + 8192 + wave * 1024);
      gload_lds16(vs_ + 4096 + tid * 16, db + 12288 + wave * 1024);
    }

    // ---- S-MFMAs: mt0 then mt1 (kfa regs die before kfb loads -> low peak) ----
    f32x16 sA = fzero16(), sB = fzero16();
    {
      bf16x8 kf[4];
#pragma unroll
      for (int ks = 0; ks < 4; ++ks)
        kf[ks] = *(const bf16x8*)(Kc + ks * 512 + lane * 8);
      __builtin_amdgcn_s_setprio(1);
#pragma unroll
      for (int ks = 0; ks < 4; ++ks) sA = MFMA32(kf[ks], qf[ks], sA);
      __builtin_amdgcn_s_setprio(0);
    }
    {
      bf16x8 kf[4];
#pragma unroll
      for (int ks = 0; ks < 4; ++ks)
        kf[ks] = *(const bf16x8*)(Kc + 2048 + ks * 512 + lane * 8);
      __builtin_amdgcn_s_setprio(1);
#pragma unroll
      for (int ks = 0; ks < 4; ++ks) sB = MFMA32(kf[ks], qf[ks], sB);
      __builtin_amdgcn_s_setprio(0);
    }

    // V frags from LDS (issue early; land during ptrans)
    bf16x8 vf[2][4];
#pragma unroll
    for (int dt = 0; dt < 2; ++dt)
#pragma unroll
      for (int ks = 0; ks < 4; ++ks)
        vf[dt][ks] = *(const bf16x8*)(Vc + dt * 2048 + ks * 512 + lane * 8);

    // ---- ptrans mt0 -> PV mt0; ptrans mt1 overlaps PV mt0 drain ----
    bf16x8 fA0, fA1, fB0, fB1;
    ptrans(sA, rsum, fA0, fA1);
    __builtin_amdgcn_s_setprio(1);
    o[0] = MFMA32(vf[0][0], fA0, o[0]);
    o[1] = MFMA32(vf[1][0], fA0, o[1]);
    o[0] = MFMA32(vf[0][1], fA1, o[0]);
    o[1] = MFMA32(vf[1][1], fA1, o[1]);
    __builtin_amdgcn_s_setprio(0);
    ptrans(sB, rsum, fB0, fB1);
    __builtin_amdgcn_s_setprio(1);
    o[0] = MFMA32(vf[0][2], fB0, o[0]);
    o[1] = MFMA32(vf[1][2], fB0, o[1]);
    o[0] = MFMA32(vf[0][3], fB1, o[0]);
    o[1] = MFMA32(vf[1][3], fB1, o[1]);
    __builtin_amdgcn_s_setprio(0);

    // all reads of this buffer done; staged next buffer drained (vmcnt 0 in
    // __syncthreads) -> safe to swap
    __syncthreads();
  }

  // normalize + write bf16 chunk partial. O^T: d=dt*32+4*lh+8*g+t, q=l31
  unsigned short* cB = chunk ? c1 : c0;
  const int b = bh >> 4, h = bh & 15;
  float lsum = rsum + __shfl_xor(rsum, 32);
  float inv = 1.f / lsum;
  int s = q0 + l31;
#pragma unroll
  for (int dt = 0; dt < 2; ++dt)
#pragma unroll
    for (int g = 0; g < 4; ++g) {
      int d = dt * 32 + 4 * lh + 8 * g;
      size_t idx = ((size_t)(b * 2048 + s)) * 1024 + h * 64 + d;
      ushort4 hv;
#pragma unroll
      for (int t = 0; t < 4; ++t)
        ((unsigned short*)&hv)[t] = f2bf(o[dt][g * 4 + t] * inv);
      *(ushort4*)(cB + idx) = hv;
    }
}

// ---------------- K3b: combine chunk partials: attnB = bf16(c0 + c1) ----------------
__global__ __launch_bounds__(256) void k_comb(const unsigned short* __restrict__ c0,
                                              const unsigned short* __restrict__ c1,
                                              unsigned short* __restrict__ outB,
                                              int n8) {
  int i = blockIdx.x * blockDim.x + threadIdx.x;
  if (i >= n8) return;
  uint4 a = ((const uint4*)c0)[i];
  uint4 b = ((const uint4*)c1)[i];
  uint4 r;
  const unsigned short* pa = (const unsigned short*)&a;
  const unsigned short* pb = (const unsigned short*)&b;
  unsigned short* pr = (unsigned short*)&r;
#pragma unroll
  for (int j = 0; j < 8; ++j) pr[j] = f2bf(bf2f(pa[j]) + bf2f(pb[j]));
  ((uint4*)outB)[i] = r;
}

// ---------------- K4: output projection, 128x64 tiles for 2 blocks/CU ----------------
__global__ __launch_bounds__(256, 2) void k_out(const unsigned short* __restrict__ A,
                                                const unsigned short* __restrict__ B,
                                                float* __restrict__ out) {
  __shared__ unsigned short Ah[128 * 32], Bh[64 * 32];  // 8KB, 4KB
  const int tid = threadIdx.x;
  const int bm = blockIdx.y, n0 = blockIdx.x * 64;
  const int lane = tid & 63, wave = tid >> 6;
  const int wm = (wave & 1) * 64, wn = (wave >> 1) * 32;
  const int l15 = lane & 15, lq = lane >> 4;

  f32x4 acc[4][2];
#pragma unroll
  for (int i = 0; i < 4; i++)
#pragma unroll
    for (int j = 0; j < 2; j++) acc[i][j] = (f32x4){0.f, 0.f, 0.f, 0.f};

  const char* baseA = (const char*)A + (size_t)(bm * 128) * 2048;
  const char* baseB = (const char*)B + (size_t)n0 * 2048;
  const int off0 = tid << 4, row0 = off0 >> 6, seg0 = off0 & 63;
  const int off1 = (tid + 256) << 4, row1 = off1 >> 6, seg1 = off1 & 63;

  for (int k0 = 0; k0 < 1024; k0 += 32) {
    __syncthreads();
    gload_lds16(baseA + (size_t)row0 * 2048 + k0 * 2 + seg0, (char*)Ah + wave * 1024);
    gload_lds16(baseA + (size_t)row1 * 2048 + k0 * 2 + seg1,
                (char*)Ah + 4096 + wave * 1024);
    gload_lds16(baseB + (size_t)row0 * 2048 + k0 * 2 + seg0, (char*)Bh + wave * 1024);
    __syncthreads();
    bf16x8 ah[4], bh[2];
#pragma unroll
    for (int i = 0; i < 4; ++i)
      ah[i] = *(const bf16x8*)&Ah[(wm + i * 16 + l15) * 32 + lq * 8];
#pragma unroll
    for (int j = 0; j < 2; ++j)
      bh[j] = *(const bf16x8*)&Bh[(wn + j * 16 + l15) * 32 + lq * 8];
#pragma unroll
    for (int i = 0; i < 4; ++i)
#pragma unroll
      for (int j = 0; j < 2; ++j) acc[i][j] = MFMA16(ah[i], bh[j], acc[i][j]);
  }
#pragma unroll
  for (int i = 0; i < 4; ++i)
#pragma unroll
    for (int j = 0; j < 2; ++j) {
      int colw = n0 + wn + j * 16 + l15;
#pragma unroll
      for (int r = 0; r < 4; ++r) {
        int rowg = bm * 128 + wm + i * 16 + lq * 4 + r;
        out[(size_t)rowg * 1024 + colw] = acc[i][j][r];
      }
    }
}

// ---------------- launch ----------------
extern "C" void kernel_launch(void* const* d_in, const int* in_sizes, int n_in,
                              void* d_out, int out_size, void* d_ws, size_t ws_size,
                              hipStream_t stream) {
  const float* hs = (const float*)d_in[0];
  const float* freqs = (const float*)d_in[1];
  const float* Wq = (const float*)d_in[2];
  const float* Wk = (const float*)d_in[3];
  const float* Wv = (const float*)d_in[4];
  const float* Wo = (const float*)d_in[5];
  float* out = (float*)d_out;

  const size_t MD = (size_t)4096 * 1024;
  const size_t WW = (size_t)1024 * 1024;
  unsigned short* hsH = (unsigned short*)d_ws;   // 8MB; reused as attnB
  unsigned short* WtqH = hsH + MD;
  unsigned short* WtkH = WtqH + WW;
  unsigned short* WtvH = WtkH + WW;
  unsigned short* WtoH = WtvH + WW;
  unsigned short* qB = WtoH + WW;
  unsigned short* kB = qB + MD;
  unsigned short* vB = kB + MD;
  unsigned short* c0 = vB + MD;
  unsigned short* c1 = c0 + MD;
  unsigned short* attnB = hsH;  // hs bf16 dead after k_qkv

  k_split<<<4096, 256, 0, stream>>>(hs, hsH, (int)(MD / 4));
  k_wsplit<<<dim3(32, 32, 4), 256, 0, stream>>>(Wq, Wk, Wv, Wo,
                                                WtqH, WtkH, WtvH, WtoH);
  k_qkv<<<dim3(24, 32), 256, 0, stream>>>(hsH, WtqH, WtkH, WtvH, freqs, qB, kB, vB);
  k_attn<<<1024, 256, 0, stream>>>(qB, kB, vB, c0, c1);
  k_comb<<<2048, 256, 0, stream>>>(c0, c1, attnB, (int)(MD / 8));
  k_out<<<dim3(16, 32), 256, 0, stream>>>(attnB, WtoH, out);
}